// Round 11
// baseline (257.555 us; speedup 1.0000x reference)
//
#include <hip/hip_runtime.h>
#include <hip/hip_bf16.h>

#define CCH 256
#define CQK 32
#define NHW 4096

typedef float f32x4 __attribute__((ext_vector_type(4)));
typedef _Float16 hv8 __attribute__((ext_vector_type(8)));
typedef _Float16 hv4 __attribute__((ext_vector_type(4)));
typedef __fp16 fv2 __attribute__((ext_vector_type(2)));   // cvt_pkrtz native type

// Monotone float<->uint encoding so float max == uint max (handles negatives).
__device__ __forceinline__ unsigned enc_f32(float f) {
    unsigned u = __float_as_uint(f);
    return (u & 0x80000000u) ? ~u : (u | 0x80000000u);
}
__device__ __forceinline__ float dec_f32(unsigned u) {
    return __uint_as_float((u & 0x80000000u) ? (u ^ 0x80000000u) : ~u);
}

// ---------------------------------------------------------------------------
// Prep kernel: (a) convert Wall = concat(b_w, c_w, d_w) fp32 -> fp16 [320][256];
// (b) init m_enc = 0. Grid 144 x 256.  (round-5 verified, unchanged)
// ---------------------------------------------------------------------------
__global__ __launch_bounds__(256) void prep_kernel(
    const float* __restrict__ b_w, const float* __restrict__ c_w,
    const float* __restrict__ d_w, _Float16* __restrict__ Wh,
    unsigned* __restrict__ m_enc)
{
    const int bid = blockIdx.x, tid = threadIdx.x;
    if (bid < 80) {
        const int idx = (bid * 256 + tid) * 4;
        const int row = idx >> 8, col = idx & 255;
        const float* src = (row < 32) ? (b_w + row * CCH + col)
                         : (row < 64) ? (c_w + (row - 32) * CCH + col)
                                      : (d_w + (row - 64) * CCH + col);
        float4 v = *reinterpret_cast<const float4*>(src);
        _Float16* dst = Wh + (size_t)row * CCH + col;
        dst[0] = (_Float16)v.x; dst[1] = (_Float16)v.y;
        dst[2] = (_Float16)v.z; dst[3] = (_Float16)v.w;
    } else {
        m_enc[(bid - 80) * 256 + tid] = 0u;
    }
}

// ---------------------------------------------------------------------------
// Projection kernel (round-6/7 verified, unchanged). D[m=pos][n=ch].
// Grid: 4 batches x 128 position-tiles of 32. Block 256 = 4 waves.
// ---------------------------------------------------------------------------
__global__ __launch_bounds__(256) void proj_kernel(
    const float* __restrict__ a, const _Float16* __restrict__ Wh,
    const float* __restrict__ b_b, const float* __restrict__ c_b,
    const float* __restrict__ d_b,
    _Float16* __restrict__ bqT, _Float16* __restrict__ ckT,
    _Float16* __restrict__ dv)
{
    __shared__ _Float16 aT[32][CCH + 24];   // [pos][ch]; stride 560 B (16B-mult)

    const int n    = blockIdx.x >> 7;
    const int i0   = (blockIdx.x & 127) << 5;
    const int tid  = threadIdx.x;
    const int lane = tid & 63;
    const int wave = tid >> 6;
    const int l15  = lane & 15;
    const int quad = lane >> 4;

    {
        const float* ap = a + (size_t)(n*CCH + tid)*NHW + i0;
        #pragma unroll
        for (int j = 0; j < 8; ++j) {
            float4 v = *reinterpret_cast<const float4*>(ap + j*4);
            aT[j*4+0][tid] = (_Float16)v.x;
            aT[j*4+1][tid] = (_Float16)v.y;
            aT[j*4+2][tid] = (_Float16)v.z;
            aT[j*4+3][tid] = (_Float16)v.w;
        }
    }
    __syncthreads();

    const f32x4 zf = {0.f, 0.f, 0.f, 0.f};
    f32x4 acc[5][2];
    #pragma unroll
    for (int t = 0; t < 5; ++t) { acc[t][0] = zf; acc[t][1] = zf; }

    const int ch0w = wave * 80;

    #pragma unroll
    for (int ks = 0; ks < 8; ++ks) {
        const int k0 = ks * 32;
        hv8 af0 = *reinterpret_cast<const hv8*>(&aT[l15][k0 + quad*8]);
        hv8 af1 = *reinterpret_cast<const hv8*>(&aT[16 + l15][k0 + quad*8]);
        #pragma unroll
        for (int t = 0; t < 5; ++t) {
            const int ch0 = ch0w + t*16;
            hv8 bf = *reinterpret_cast<const hv8*>(
                Wh + (size_t)(ch0 + l15)*CCH + k0 + quad*8);
            acc[t][0] = __builtin_amdgcn_mfma_f32_16x16x32_f16(af0, bf, acc[t][0], 0, 0, 0);
            acc[t][1] = __builtin_amdgcn_mfma_f32_16x16x32_f16(af1, bf, acc[t][1], 0, 0, 0);
        }
    }

    const int pos_b = i0 + quad*4;
    #pragma unroll
    for (int t = 0; t < 5; ++t) {
        const int ch0 = ch0w + t*16;
        if (ch0 < 64) {
            const float* bias_arr = (ch0 < 32) ? b_b : c_b;
            _Float16*    outp     = (ch0 < 32) ? bqT : ckT;
            const int    ch       = (ch0 & 31) + l15;
            const float  bias     = bias_arr[ch];
            #pragma unroll
            for (int nf = 0; nf < 2; ++nf) {
                #pragma unroll
                for (int r = 0; r < 4; ++r) {
                    const int pos = pos_b + nf*16 + r;
                    outp[((size_t)n*NHW + pos)*CQK + ch] =
                        (_Float16)(acc[t][nf][r] + bias);
                }
            }
        } else {
            const int ch   = ch0 - 64 + l15;
            const float bias = d_b[ch];
            #pragma unroll
            for (int nf = 0; nf < 2; ++nf) {
                hv4 v = { (_Float16)(acc[t][nf][0] + bias),
                          (_Float16)(acc[t][nf][1] + bias),
                          (_Float16)(acc[t][nf][2] + bias),
                          (_Float16)(acc[t][nf][3] + bias) };
                *reinterpret_cast<hv4*>(
                    dv + ((size_t)n*CCH + ch)*NHW + pos_b + nf*16) = v;
            }
        }
    }
}

// ---------------------------------------------------------------------------
// Pass A: per-q-row max, transposed S^T = K Q^T (round-9 verified, unchanged).
// Grid: 4n x 64qt x 4 k-splits = 1024.
// ---------------------------------------------------------------------------
__global__ __launch_bounds__(256) void rowmax_kernel(
    const _Float16* __restrict__ bqT, const _Float16* __restrict__ ckT,
    unsigned* __restrict__ m_enc)
{
    const int bx   = blockIdx.x;
    const int n    = bx >> 8;
    const int qt   = (bx >> 2) & 63;
    const int ks   = bx & 3;
    const int q0   = qt << 6;
    const int tid  = threadIdx.x;
    const int wave = tid >> 6;
    const int lane = tid & 63;
    const int l15  = lane & 15;
    const int quad = lane >> 4;

    const f32x4 zf = {0.f, 0.f, 0.f, 0.f};
    const hv8 qf = *reinterpret_cast<const hv8*>(
        bqT + ((size_t)n*NHW + q0 + wave*16 + l15)*CQK + quad*8);

    float mx = -1e30f;

    for (int kt = ks*16; kt < ks*16 + 16; ++kt) {
        const int k0 = kt << 6;
        #pragma unroll
        for (int f = 0; f < 4; ++f) {
            hv8 kf = *reinterpret_cast<const hv8*>(
                ckT + ((size_t)n*NHW + k0 + f*16 + l15)*CQK + quad*8);
            f32x4 s = __builtin_amdgcn_mfma_f32_16x16x32_f16(kf, qf, zf, 0, 0, 0);
            mx = fmaxf(mx, fmaxf(fmaxf(s[0], s[1]), fmaxf(s[2], s[3])));
        }
    }
    // reduce across quads (same l15 = same q)
    mx = fmaxf(mx, __shfl_xor(mx, 16, 64));
    mx = fmaxf(mx, __shfl_xor(mx, 32, 64));
    if (lane < 16)
        atomicMax(&m_enc[n*NHW + q0 + wave*16 + l15], enc_f32(mx));
}

// ---------------------------------------------------------------------------
// Pass B: flash attention, fixed row max. BARRIER-FREE, V-FROM-GLOBAL:
// V fragments [co=t*16+l15][k+quad*8] are 16B-contiguous in dv's global
// layout, so each wave loads them directly (global b128). The 4 waves of a
// block read identical V/K addresses -> L1-served. No dv_lds, no staging,
// no __syncthreads anywhere -> waves fully independent (the r6 convoy
// failure mode at low blocks/CU does not apply).
// 32 q per wave (2 qf frags) halves V traffic per q. Per-wave p_lds is
// double-buffered: softmax(kt+1) overlaps PV(kt) (r10-verified pipeline).
// Grid: 512 blocks x 256 thr; q-tile 128, co-split 4. blockIdx swizzled
// ((n,cg) in low 4 bits) so each XCD's L2 sees few dv slices.
// ---------------------------------------------------------------------------
__global__ __launch_bounds__(256, 2) void attn_kernel(
    const _Float16* __restrict__ bqT, const _Float16* __restrict__ ckT,
    const _Float16* __restrict__ dv, const unsigned* __restrict__ m_enc,
    const float* __restrict__ a, const float* __restrict__ alpha_p,
    float* __restrict__ out)
{
    __shared__ _Float16 p_lds[2][4][32 * 72];   // dbuf per-wave P, 36.9 KB

    const int bx   = blockIdx.x;
    const int ncg  = bx & 15;
    const int n    = ncg >> 2;
    const int cg   = ncg & 3;
    const int q0   = (bx >> 4) << 7;        // 32 tiles of 128 q
    const int co0  = cg << 6;
    const int tid  = threadIdx.x;
    const int wave = tid >> 6;
    const int lane = tid & 63;
    const int l15  = lane & 15;
    const int quad = lane >> 4;

    const f32x4 zf = {0.f, 0.f, 0.f, 0.f};
    const float L2E = 1.4426950408889634f;
    const _Float16 one_h = (_Float16)1.0f;
    const hv8 ones = { one_h, one_h, one_h, one_h, one_h, one_h, one_h, one_h };

    const int qb = q0 + wave*32;            // this wave's 32-q base

    hv8   qf[2];
    float mneg[2];
    #pragma unroll
    for (int qh = 0; qh < 2; ++qh) {
        qf[qh] = *reinterpret_cast<const hv8*>(
            bqT + ((size_t)n*NHW + qb + qh*16 + l15)*CQK + quad*8);
        mneg[qh] = -L2E * dec_f32(m_enc[n*NHW + qb + qh*16 + l15]);
    }

    f32x4 acc[2][4];
    #pragma unroll
    for (int qh = 0; qh < 2; ++qh)
        #pragma unroll
        for (int t = 0; t < 4; ++t) acc[qh][t] = zf;
    f32x4 acc_l[2] = { zf, zf };

    const _Float16* ckbase = ckT + ((size_t)n*NHW + l15)*CQK + quad*8;
    const _Float16* dvbase = dv + ((size_t)(n*CCH + co0 + l15))*NHW + quad*8;

    // S^T/exp for a key tile -> p_lds[buf]  (per-wave region, no barrier)
    auto softmax_tile = [&](int buf, const hv8* kf) {
        #pragma unroll
        for (int f = 0; f < 4; ++f) {
            #pragma unroll
            for (int qh = 0; qh < 2; ++qh) {
                f32x4 s = __builtin_amdgcn_mfma_f32_16x16x32_f16(kf[f], qf[qh], zf, 0, 0, 0);
                float p0 = __builtin_amdgcn_exp2f(fmaf(s[0], L2E, mneg[qh]));
                float p1 = __builtin_amdgcn_exp2f(fmaf(s[1], L2E, mneg[qh]));
                float p2 = __builtin_amdgcn_exp2f(fmaf(s[2], L2E, mneg[qh]));
                float p3 = __builtin_amdgcn_exp2f(fmaf(s[3], L2E, mneg[qh]));
                fv2 lo = __builtin_amdgcn_cvt_pkrtz(p0, p1);
                fv2 hi = __builtin_amdgcn_cvt_pkrtz(p2, p3);
                uint2 w;
                w.x = __builtin_bit_cast(unsigned, lo);
                w.y = __builtin_bit_cast(unsigned, hi);
                *reinterpret_cast<uint2*>(
                    &p_lds[buf][wave][(qh*16 + l15)*72 + f*16 + quad*4]) = w;
            }
        }
    };

    // ---- prologue: softmax tile 0 into buf 0
    {
        hv8 kf0[4];
        #pragma unroll
        for (int f = 0; f < 4; ++f)
            kf0[f] = *reinterpret_cast<const hv8*>(ckbase + (size_t)(f*16)*CQK);
        softmax_tile(0, kf0);
    }

    for (int kt = 0; kt < 64; ++kt) {
        const int k0  = kt << 6;
        const int cur = kt & 1;

        // ---- V fragments for THIS tile: direct global b128 (L1-shared)
        hv8 d[4][2];
        #pragma unroll
        for (int t = 0; t < 4; ++t) {
            d[t][0] = *reinterpret_cast<const hv8*>(
                dvbase + (size_t)(t*16)*NHW + k0);
            d[t][1] = *reinterpret_cast<const hv8*>(
                dvbase + (size_t)(t*16)*NHW + k0 + 32);
        }

        // ---- softmax(kt+1) into the other p buffer (overlaps V loads above)
        if (kt < 63) {
            hv8 kfn[4];
            #pragma unroll
            for (int f = 0; f < 4; ++f)
                kfn[f] = *reinterpret_cast<const hv8*>(
                    ckbase + (size_t)(k0 + 64 + f*16)*CQK);
            softmax_tile(cur ^ 1, kfn);
        }

        // ---- PV(kt): p from p_lds[cur] (written last iter, same wave)
        hv8 pf[2][2];
        #pragma unroll
        for (int qh = 0; qh < 2; ++qh) {
            pf[qh][0] = *reinterpret_cast<const hv8*>(
                &p_lds[cur][wave][(qh*16 + l15)*72 + quad*8]);
            pf[qh][1] = *reinterpret_cast<const hv8*>(
                &p_lds[cur][wave][(qh*16 + l15)*72 + 32 + quad*8]);
        }
        #pragma unroll
        for (int t = 0; t < 4; ++t) {
            #pragma unroll
            for (int qh = 0; qh < 2; ++qh) {
                acc[qh][t] = __builtin_amdgcn_mfma_f32_16x16x32_f16(pf[qh][0], d[t][0], acc[qh][t], 0, 0, 0);
                acc[qh][t] = __builtin_amdgcn_mfma_f32_16x16x32_f16(pf[qh][1], d[t][1], acc[qh][t], 0, 0, 0);
            }
        }
        #pragma unroll
        for (int qh = 0; qh < 2; ++qh) {
            acc_l[qh] = __builtin_amdgcn_mfma_f32_16x16x32_f16(pf[qh][0], ones, acc_l[qh], 0, 0, 0);
            acc_l[qh] = __builtin_amdgcn_mfma_f32_16x16x32_f16(pf[qh][1], ones, acc_l[qh], 0, 0, 0);
        }
    }

    // ---- epilogue: out[co][q..q+3] = alpha*O/l + a, direct float4 per lane
    const float alpha = alpha_p[0];
    #pragma unroll
    for (int qh = 0; qh < 2; ++qh) {
        f32x4 rl;
        #pragma unroll
        for (int r = 0; r < 4; ++r) rl[r] = alpha / acc_l[qh][r];
        const int qv = qb + qh*16 + quad*4;
        #pragma unroll
        for (int t = 0; t < 4; ++t) {
            const int co = co0 + t*16 + l15;
            const size_t off = ((size_t)n*CCH + co)*NHW + qv;
            float4 av = *reinterpret_cast<const float4*>(a + off);
            float4 o;
            o.x = acc[qh][t][0]*rl[0] + av.x;
            o.y = acc[qh][t][1]*rl[1] + av.y;
            o.z = acc[qh][t][2]*rl[2] + av.z;
            o.w = acc[qh][t][3]*rl[3] + av.w;
            *reinterpret_cast<float4*>(out + off) = o;
        }
    }
}

extern "C" void kernel_launch(void* const* d_in, const int* in_sizes, int n_in,
                              void* d_out, int out_size, void* d_ws, size_t ws_size,
                              hipStream_t stream)
{
    const float* a    = (const float*)d_in[0];
    const float* b_w  = (const float*)d_in[1];
    const float* b_b  = (const float*)d_in[2];
    const float* c_w  = (const float*)d_in[3];
    const float* c_b  = (const float*)d_in[4];
    const float* d_w  = (const float*)d_in[5];
    const float* d_b  = (const float*)d_in[6];
    const float* alp  = (const float*)d_in[7];
    float* out = (float*)d_out;

    _Float16* bqT  = (_Float16*)d_ws;                 // [4][4096][32] fp16, 1 MB
    _Float16* ckT  = bqT + (size_t)4*NHW*CQK;         // [4][4096][32] fp16, 1 MB
    _Float16* dv   = ckT + (size_t)4*NHW*CQK;         // [4][256][4096] fp16, 8 MB
    unsigned* m_enc = (unsigned*)(dv + (size_t)4*CCH*NHW);  // [4][4096] u32, 64 KB
    _Float16* Wh   = (_Float16*)(m_enc + 4*NHW);      // [320][256] fp16, 160 KB

    prep_kernel<<<144, 256, 0, stream>>>(b_w, c_w, d_w, Wh, m_enc);
    proj_kernel<<<512, 256, 0, stream>>>(a, Wh, b_b, c_b, d_b, bqT, ckT, dv);
    rowmax_kernel<<<1024, 256, 0, stream>>>(bqT, ckT, m_enc);
    attn_kernel<<<512, 256, 0, stream>>>(bqT, ckT, dv, m_enc, a, alp, out);
}